// Round 12
// baseline (674.303 us; speedup 1.0000x reference)
//
#include <hip/hip_runtime.h>
#include <hip/hip_cooperative_groups.h>
#include <hip/hip_bf16.h>

namespace cg = cooperative_groups;

// GCN 2-layer forward on gfx950 — single cooperative CSR-build kernel,
// group-per-row packed fp16 gathers, fused fp16-MFMA MLP. 5 launches total.
//
//   k_build (cooperative): bucket hist -> scans -> register-scatter ->
//       per-bucket node CSR (self-inclusive, byte-offset ssrc) + dinv +
//       xh = fp16(dinv ⊙ x)
//   k_prep: W1/W2 -> MFMA B-frag fp16 + zero rows xh[N], yh[N]
//   gather1: t = fp16(dinv[d] * Σ xh[s])
//   k_mlp:  h = relu(t W1 + b1) in regs; yh = fp16(dinv ⊙ (h W2)) pad 64
//   gather2: out = dinv[d] * Σ yh[s] + b2
//
// R12: R11's 5-kernel CSR chain + prescale + zrows (~60us incl. 7 launch
// gaps, ei read twice, cntmat HBM round-trip) fused into one cooperative
// kernel: edges read ONCE into registers, 4 grid.sync()s, p2 reads tmp
// L2/L3-hot, prescale folded per bucket. Launches 14 -> 5.

static constexpr int FIN = 64;
static constexpr int HID = 128;
static constexpr int CLS = 40;
static constexpr int NB_MAX = 392;   // buckets of 256 nodes; N <= 100352
static constexpr int NWG_B = 256;    // build workgroups (1 per CU)
static constexpr int EPT = 7;        // edges per thread (7*1024 >= E/256)

typedef _Float16 half8 __attribute__((ext_vector_type(8)));
typedef _Float16 half4v __attribute__((ext_vector_type(4)));
typedef _Float16 half2v __attribute__((ext_vector_type(2)));
typedef float floatx4 __attribute__((ext_vector_type(4)));

// ---------------- cooperative CSR build + prescale ----------------

__global__ __launch_bounds__(1024, 4) void k_build(
    const int* __restrict__ ei, const float* __restrict__ x,
    int* __restrict__ cntmat, int* __restrict__ btot, int* __restrict__ bbase,
    int* __restrict__ rstart, int* __restrict__ cnt, float* __restrict__ dinv,
    int* __restrict__ ssrc, unsigned* __restrict__ tmp,
    _Float16* __restrict__ xh, int E, int N, int NB, int per_wg) {
    cg::grid_group grid = cg::this_grid();
    __shared__ int lh[NB_MAX];     // bucket hist / bucket cursors / node cursors
    __shared__ int sd[512];        // scan buffer / node hist
    __shared__ float dvv[256];
    const int tid = threadIdx.x, wg = blockIdx.x;

    // ---- Phase A: bucket histogram; edges cached in registers ----
    unsigned w[EPT];
    int bk[EPT];
    for (int i = tid; i < NB; i += 1024) lh[i] = 0;
    __syncthreads();
    const int r0 = wg * per_wg, r1 = min(E, r0 + per_wg);
#pragma unroll
    for (int j = 0; j < EPT; ++j) {
        const int e = r0 + j * 1024 + tid;
        bk[j] = -1;
        if (e < r1) {
            const int s = ei[e], d = ei[E + e];
            bk[j] = d >> 8;
            w[j] = ((unsigned)(d & 255) << 24) | (unsigned)s;
            atomicAdd(&lh[bk[j]], 1);
        }
    }
    __syncthreads();
    for (int b = tid; b < NB; b += 1024) cntmat[b * NWG_B + wg] = lh[b];
    __threadfence();
    grid.sync();

    // ---- Phase B1: exclusive scan of each bucket row across WGs ----
    for (int row = wg; row < NB; row += NWG_B) {
        int v = (tid < NWG_B) ? cntmat[row * NWG_B + tid] : 0;
        if (tid < NWG_B) sd[tid] = v;
        for (int off = 1; off < NWG_B; off <<= 1) {
            __syncthreads();
            int t = (tid >= off && tid < NWG_B) ? sd[tid - off] : 0;
            __syncthreads();
            if (tid < NWG_B) sd[tid] += t;
        }
        __syncthreads();
        if (tid < NWG_B) cntmat[row * NWG_B + tid] = sd[tid] - v;
        if (tid == NWG_B - 1) btot[row] = sd[tid];
        __syncthreads();
    }
    __threadfence();
    grid.sync();

    // ---- Phase B2: WG 0 scans bucket totals -> bbase ----
    if (wg == 0) {
        int v = (tid < NB) ? btot[tid] : 0;
        if (tid < 512) sd[tid] = (tid < NB) ? v : 0;
        for (int off = 1; off < 512; off <<= 1) {
            __syncthreads();
            int t = (tid >= off && tid < 512) ? sd[tid - off] : 0;
            __syncthreads();
            if (tid < 512) sd[tid] += t;
        }
        __syncthreads();
        if (tid < NB) bbase[tid] = sd[tid] - v;
        if (tid == 0) bbase[NB] = E;
    }
    __threadfence();
    grid.sync();

    // ---- Phase C: scatter cached edges to reserved bucket ranges ----
    for (int b = tid; b < NB; b += 1024)
        lh[b] = cntmat[b * NWG_B + wg] + bbase[b];
    __syncthreads();
#pragma unroll
    for (int j = 0; j < EPT; ++j) {
        if (bk[j] >= 0) {
            const int pos = atomicAdd(&lh[bk[j]], 1);
            tmp[pos] = w[j];
        }
    }
    __threadfence();
    grid.sync();

    // ---- Phase D: per-bucket node CSR + dinv + prescale ----
    for (int b = wg; b < NB; b += NWG_B) {
        const int node0 = b << 8;
        const int e0 = bbase[b], e1 = bbase[b + 1];
        if (tid < 256) sd[tid] = 0;
        __syncthreads();
        for (int e = e0 + tid; e < e1; e += 1024)
            atomicAdd(&sd[tmp[e] >> 24], 1);
        __syncthreads();
        const int v = (tid < 256) ? sd[tid] : 0;
        for (int off = 1; off < 256; off <<= 1) {
            __syncthreads();
            int t = (tid >= off && tid < 256) ? sd[tid - off] : 0;
            __syncthreads();
            if (tid < 256) sd[tid] += t;
        }
        __syncthreads();
        int rs = 0;
        if (tid < 256) {
            rs = e0 + node0 + (sd[tid] - v) + tid;   // self-inclusive layout
            const int node = node0 + tid;
            if (node < N) {
                rstart[node] = rs;
                cnt[node] = v + 1;
                const float dv = rsqrtf((float)v + 1.0f);
                dinv[node] = dv;
                dvv[tid] = dv;
                ssrc[rs] = node << 7;                // self entry (byte offset)
            }
            lh[tid] = rs + 1;                        // node cursor
        }
        __syncthreads();
        // prescale this bucket's rows: xh = fp16(dinv * x)
        const int nrows = min(256, N - node0);
        for (int i = tid; i < nrows * 16; i += 1024) {
            const int r = i >> 4, c4 = i & 15;
            const float dv = dvv[r];
            const float4 vv = *(const float4*)&x[(((size_t)(node0 + r)) << 6) + c4 * 4];
            half4v o;
            o[0] = (_Float16)(dv * vv.x); o[1] = (_Float16)(dv * vv.y);
            o[2] = (_Float16)(dv * vv.z); o[3] = (_Float16)(dv * vv.w);
            *(half4v*)(xh + (((size_t)(node0 + r)) << 6) + c4 * 4) = o;
        }
        // permute edges into final slots (byte offsets)
        for (int e = e0 + tid; e < e1; e += 1024) {
            const unsigned p = tmp[e];
            const int slot = atomicAdd(&lh[p >> 24], 1);
            ssrc[slot] = (int)(p & 0xFFFFFFu) << 7;
        }
        __syncthreads();
    }
}

// ---------------- weight prep + zero rows ----------------
// B frag (16x16x32): lane holds B[k = quad*8+j][n = lane&15], j=0..7.

__global__ __launch_bounds__(256) void k_prep(const float* __restrict__ W1,
                                              const float* __restrict__ W2,
                                              _Float16* __restrict__ w1f,
                                              _Float16* __restrict__ w2f,
                                              _Float16* __restrict__ xh,
                                              _Float16* __restrict__ yh, int N) {
    const int idx = blockIdx.x * 256 + threadIdx.x;
    if (idx < 1024) {                       // W1: nt 0..7, kk 0..1, lane
        const int lane = idx & 63;
        const int kk = (idx >> 6) & 1;
        const int nt = idx >> 7;
        const int quad = lane >> 4, col = lane & 15;
        half8 o;
#pragma unroll
        for (int j = 0; j < 8; ++j) {
            const int k = kk * 32 + quad * 8 + j;
            const int n = nt * 16 + col;
            o[j] = (_Float16)W1[k * HID + n];
        }
        *(half8*)(w1f + (size_t)idx * 8) = o;
    } else if (idx < 1024 + 768) {          // W2: nt 0..2, kk 0..3, lane (n pad 48)
        const int i2 = idx - 1024;
        const int lane = i2 & 63;
        const int kk = (i2 >> 6) & 3;
        const int nt = i2 >> 8;
        const int quad = lane >> 4, col = lane & 15;
        half8 o;
#pragma unroll
        for (int j = 0; j < 8; ++j) {
            const int k = kk * 32 + quad * 8 + j;
            const int n = nt * 16 + col;
            o[j] = (n < CLS) ? (_Float16)W2[k * CLS + n] : (_Float16)0.f;
        }
        *(half8*)(w2f + (size_t)i2 * 8) = o;
    } else if (idx < 1024 + 768 + 64) {     // zero rows xh[N], yh[N]
        const int t = idx - 1792;
        xh[(size_t)N * 64 + t] = (_Float16)0;
        yh[(size_t)N * 64 + t] = (_Float16)0;
    }
}

// ---------------- group-per-row packed fp16 gather ----------------
// X: fp16 rows of 64 halves (128B), row N = zeros. Wave handles 8 rows:
// group g (8 lanes) owns row wave*8+g; lane owns 16B chunk sub. Edges
// accumulate serially in-lane (4 pk_add each) — no reduction. OOB slots
// broadcast the zero-row offset. ssrc entries are BYTE offsets.

template <bool HALF_OUT, int FOUT, bool BIAS>
__global__ __launch_bounds__(256) void k_gather8(const _Float16* __restrict__ X,
                                                 const float* __restrict__ dinv,
                                                 const int* __restrict__ rstart,
                                                 const int* __restrict__ cnt,
                                                 const int* __restrict__ ssrc,
                                                 const float* __restrict__ bias,
                                                 void* __restrict__ outv,
                                                 int N, int zoff) {
    const int wave = (blockIdx.x * 256 + threadIdx.x) >> 6;
    const int lane = threadIdx.x & 63;
    const int g = lane >> 3, sub = lane & 7;
    const int r = wave * 8 + g;
    const int rc = min(r, N - 1);
    const int st = rstart[rc];
    const int total = cnt[rc];             // self-inclusive, >= 1
    int maxtot = total;                    // wave-max iteration bound
    maxtot = max(maxtot, __shfl_xor(maxtot, 8));
    maxtot = max(maxtot, __shfl_xor(maxtot, 16));
    maxtot = max(maxtot, __shfl_xor(maxtot, 32));
    const char* Xb = (const char*)X;
    half2v acc2[4] = {half2v{0, 0}, half2v{0, 0}, half2v{0, 0}, half2v{0, 0}};
    for (int base = 0; base < maxtot; base += 8) {
        const int idx = base + sub;
        int myO = ssrc[st + min(idx, total - 1)];
        myO = (idx < total) ? myO : zoff;  // OOB -> zero row
#pragma unroll
        for (int jj = 0; jj < 8; ++jj) {
            const int off = __shfl(myO, g * 8 + jj);
            const half8 hv = *(const half8*)(Xb + off + (sub << 4));
            const half2v* h2 = (const half2v*)&hv;
            acc2[0] += h2[0]; acc2[1] += h2[1];
            acc2[2] += h2[2]; acc2[3] += h2[3];
        }
    }
    if (r >= N) return;
    const float dv = dinv[rc];
    float acc[8];
#pragma unroll
    for (int k = 0; k < 8; ++k) acc[k] = (float)acc2[k >> 1][k & 1] * dv;
    if (HALF_OUT) {
        half8 o;
#pragma unroll
        for (int k = 0; k < 8; ++k) o[k] = (_Float16)acc[k];
        *(half8*)((_Float16*)outv + ((size_t)r << 6) + (sub << 3)) = o;
    } else {
        const int f0 = sub * 8;
        if (f0 < FOUT) {
            if (BIAS) {
                float4 bb0 = *(const float4*)&bias[f0];
                float4 bb1 = *(const float4*)&bias[f0 + 4];
                acc[0] += bb0.x; acc[1] += bb0.y; acc[2] += bb0.z; acc[3] += bb0.w;
                acc[4] += bb1.x; acc[5] += bb1.y; acc[6] += bb1.z; acc[7] += bb1.w;
            }
            float* op = (float*)outv + (size_t)r * FOUT + f0;
            *(float4*)op = make_float4(acc[0], acc[1], acc[2], acc[3]);
            *(float4*)(op + 4) = make_float4(acc[4], acc[5], acc[6], acc[7]);
        }
    }
}

// ---------------- fused MFMA MLP: t -> h (regs) -> yh ----------------

__global__ __launch_bounds__(256, 3) void k_mlp(const _Float16* __restrict__ th,
                                                const _Float16* __restrict__ w1f,
                                                const float* __restrict__ b1,
                                                const _Float16* __restrict__ w2f,
                                                const float* __restrict__ dinv,
                                                _Float16* __restrict__ yh, int N) {
    __shared__ _Float16 hbuf[4][16 * 128];  // 16 KB
    const int tid = threadIdx.x;
    const int wave = tid >> 6, lane = tid & 63;
    const int quad = lane >> 4, col = lane & 15;
    const int row0 = blockIdx.x * 64 + wave * 16;
    const int arow = min(row0 + col, N - 1);
    const half8 a0 = *(const half8*)(th + ((size_t)arow << 6) + quad * 8);
    const half8 a1 = *(const half8*)(th + ((size_t)arow << 6) + 32 + quad * 8);
    floatx4 c[8];
#pragma unroll
    for (int nt = 0; nt < 8; ++nt) {
        c[nt] = (floatx4){0.f, 0.f, 0.f, 0.f};
        const half8 bb0 = *(const half8*)(w1f + (size_t)((nt * 2 + 0) * 64 + lane) * 8);
        const half8 bb1 = *(const half8*)(w1f + (size_t)((nt * 2 + 1) * 64 + lane) * 8);
        c[nt] = __builtin_amdgcn_mfma_f32_16x16x32_f16(a0, bb0, c[nt], 0, 0, 0);
        c[nt] = __builtin_amdgcn_mfma_f32_16x16x32_f16(a1, bb1, c[nt], 0, 0, 0);
    }
    _Float16* hb = hbuf[wave];
#pragma unroll
    for (int nt = 0; nt < 8; ++nt) {
        const float bv = b1[nt * 16 + col];
#pragma unroll
        for (int reg = 0; reg < 4; ++reg) {
            const int r = quad * 4 + reg;
            const int hcol = nt * 16 + col;
            const int chunk = ((hcol >> 3) ^ r) & 15;
            hb[r * 128 + chunk * 8 + (hcol & 7)] =
                (_Float16)fmaxf(c[nt][reg] + bv, 0.f);
        }
    }
    __syncthreads();
    half8 a2[4];
#pragma unroll
    for (int kk = 0; kk < 4; ++kk) {
        const int chunk = ((kk * 4 + quad) ^ col) & 15;
        a2[kk] = *(const half8*)(hb + col * 128 + chunk * 8);
    }
    floatx4 c2[3];
#pragma unroll
    for (int nt = 0; nt < 3; ++nt) {
        c2[nt] = (floatx4){0.f, 0.f, 0.f, 0.f};
#pragma unroll
        for (int kk = 0; kk < 4; ++kk) {
            const half8 bb = *(const half8*)(w2f + (size_t)((nt * 4 + kk) * 64 + lane) * 8);
            c2[nt] = __builtin_amdgcn_mfma_f32_16x16x32_f16(a2[kk], bb, c2[nt], 0, 0, 0);
        }
    }
#pragma unroll
    for (int reg = 0; reg < 4; ++reg) {
        const int gr = row0 + quad * 4 + reg;
        const float dvr = dinv[min(gr, N - 1)];
#pragma unroll
        for (int nt = 0; nt < 3; ++nt) {
            const int cc = nt * 16 + col;
            if (gr < N && cc < CLS)
                yh[((size_t)gr << 6) + cc] = (_Float16)(c2[nt][reg] * dvr);
        }
    }
    for (int i = lane; i < 16 * 12; i += 64) {
        const int row = row0 + i / 12;
        if (row < N)
            ((unsigned*)(yh + ((size_t)row << 6)))[20 + i % 12] = 0u;
    }
}

// ---------------- launch ----------------

extern "C" void kernel_launch(void* const* d_in, const int* in_sizes, int n_in,
                              void* d_out, int out_size, void* d_ws, size_t ws_size,
                              hipStream_t stream) {
    const int* ei   = (const int*)d_in[1];   // [2][E]
    const float* x  = (const float*)d_in[0];
    const float* W1 = (const float*)d_in[2];
    const float* b1 = (const float*)d_in[3];
    const float* W2 = (const float*)d_in[4];
    const float* b2 = (const float*)d_in[5];
    float* out = (float*)d_out;

    int N = in_sizes[0] / FIN;
    int E = in_sizes[1] / 2;
    int NB = (N + 255) >> 8;
    int per_wg = (E + NWG_B - 1) / NWG_B;
    const int zoff = N << 7;                 // zero-row byte offset

    float* dinv    = (float*)d_ws;                       // N
    _Float16* th   = (_Float16*)(dinv + N);              // (N+1)*64
    _Float16* yh   = th + (size_t)(N + 1) * 64;          // (N+1)*64
    _Float16* xh   = yh + (size_t)(N + 1) * 64;          // (N+1)*64
    int* cnt       = (int*)(xh + (size_t)(N + 1) * 64);  // N
    int* rstart    = cnt + N;                            // N
    int* ssrc      = rstart + N;                         // E + N
    int* cntmat    = ssrc + E + N;                       // NB_MAX*NWG_B
    int* btot      = cntmat + NB_MAX * NWG_B;            // NB_MAX
    int* bbase     = btot + NB_MAX;                      // NB_MAX+1
    unsigned* tmp  = (unsigned*)(bbase + NB_MAX + 1);    // E
    _Float16* w1f  = (_Float16*)(tmp + E);               // 8192
    _Float16* w2f  = w1f + 8192;                         // 6144

    dim3 blk(256);
    // weight prep + zero rows (independent of build)
    hipLaunchKernelGGL(k_prep, dim3(8), blk, 0, stream,
                       W1, W2, w1f, w2f, xh, yh, N);
    // cooperative CSR build + dinv + prescale
    {
        void* args[] = {(void*)&ei, (void*)&x, (void*)&cntmat, (void*)&btot,
                        (void*)&bbase, (void*)&rstart, (void*)&cnt, (void*)&dinv,
                        (void*)&ssrc, (void*)&tmp, (void*)&xh,
                        (void*)&E, (void*)&N, (void*)&NB, (void*)&per_wg};
        hipLaunchCooperativeKernel((const void*)k_build, dim3(NWG_B), dim3(1024),
                                   args, 0, stream);
    }
    // layer 1 aggregate -> fp16 t
    hipLaunchKernelGGL((k_gather8<true, FIN, false>), dim3((N + 31) / 32), blk, 0, stream,
                       xh, dinv, rstart, cnt, ssrc, (const float*)nullptr, (void*)th, N, zoff);
    // fused MFMA MLP: t -> h -> yh
    hipLaunchKernelGGL(k_mlp, dim3((N + 63) / 64), blk, 0, stream, th, w1f, b1, w2f, dinv, yh, N);
    // layer 2 aggregate + bias -> out
    hipLaunchKernelGGL((k_gather8<false, CLS, true>), dim3((N + 31) / 32), blk, 0, stream,
                       yh, dinv, rstart, cnt, ssrc, b2, (void*)out, N, zoff);
}

// Round 13
// 223.728 us; speedup vs baseline: 3.0139x; 3.0139x over previous
//
#include <hip/hip_runtime.h>
#include <hip/hip_bf16.h>

// GCN 2-layer forward on gfx950 — CSR radix partition (non-cooperative; the
// R12 cooperative fusion was a 2.5x regression from grid.sync lock-step),
// degree-sorted group-per-row packed fp16 gathers, fused fp16-MFMA MLP.
//
//   k_cnt/bscan1/bscan2/k_scat: bucket partition of edges by dst>>8
//   k_p2: per-bucket node CSR (self-inclusive, byte-offset ssrc) + dinv +
//         degree counting-sort -> order[] + fused prescale xh = fp16(dinv*x)
//   k_prep: W1/W2 -> MFMA B-frag fp16 + zero rows xh[N], yh[N]
//   gather1: t[r] = fp16(dinv[r] * sum xh[s]),  r = order[wave*8+g]
//   k_mlp: h = relu(t W1 + b1) in regs; yh = fp16(dinv (h W2)) pad 64
//   gather2: out[r] = dinv[r] * sum yh[s] + b2
//
// R13: degree-sorted wave assignment removes the ~25% wave-max iteration
// waste (max-of-8 Poisson-16 ~ 23 vs mean 17) and the 3-shfl maxtot
// reduction; prescale/zrows folded into p2/prep (launches 14 -> 9).

static constexpr int FIN = 64;
static constexpr int HID = 128;
static constexpr int CLS = 40;
static constexpr int NB_MAX = 392;   // buckets of 256 nodes; N <= 100352
static constexpr int NWG_P = 256;    // partition workgroups

typedef _Float16 half8 __attribute__((ext_vector_type(8)));
typedef _Float16 half4v __attribute__((ext_vector_type(4)));
typedef _Float16 half2v __attribute__((ext_vector_type(2)));
typedef float floatx4 __attribute__((ext_vector_type(4)));

// ---------------- CSR build: radix partition by dst>>8 ----------------

__global__ __launch_bounds__(1024) void k_cnt(const int* __restrict__ dst,
                                              int* __restrict__ cntmat,
                                              int E, int NB, int per_wg) {
    __shared__ int lh[NB_MAX];
    const int tid = threadIdx.x, wg = blockIdx.x;
    for (int i = tid; i < NB; i += 1024) lh[i] = 0;
    __syncthreads();
    const int r0 = wg * per_wg, r1 = min(E, r0 + per_wg);
    for (int e = r0 + tid; e < r1; e += 1024)
        atomicAdd(&lh[dst[e] >> 8], 1);
    __syncthreads();
    for (int b = tid; b < NB; b += 1024) cntmat[b * NWG_P + wg] = lh[b];
}

__global__ __launch_bounds__(256) void k_bscan1(int* __restrict__ cntmat,
                                                int* __restrict__ btot) {
    __shared__ int sd[256];
    const int b = blockIdx.x, tid = threadIdx.x;
    int v = cntmat[b * NWG_P + tid];
    sd[tid] = v;
    for (int off = 1; off < 256; off <<= 1) {
        __syncthreads();
        int t = (tid >= off) ? sd[tid - off] : 0;
        __syncthreads();
        sd[tid] += t;
    }
    __syncthreads();
    cntmat[b * NWG_P + tid] = sd[tid] - v;
    if (tid == 255) btot[b] = sd[255];
}

__global__ __launch_bounds__(512) void k_bscan2(const int* __restrict__ btot,
                                                int* __restrict__ bbase,
                                                int NB, int E) {
    __shared__ int sd[512];
    const int tid = threadIdx.x;
    int v = (tid < NB) ? btot[tid] : 0;
    sd[tid] = v;
    for (int off = 1; off < 512; off <<= 1) {
        __syncthreads();
        int t = (tid >= off) ? sd[tid - off] : 0;
        __syncthreads();
        sd[tid] += t;
    }
    __syncthreads();
    if (tid < NB) bbase[tid] = sd[tid] - v;
    if (tid == 0) bbase[NB] = E;
}

__global__ __launch_bounds__(1024) void k_scat(const int* __restrict__ ei,
                                               const int* __restrict__ cntmat,
                                               const int* __restrict__ bbase,
                                               unsigned* __restrict__ tmp,
                                               int E, int NB, int per_wg) {
    __shared__ int lcur[NB_MAX];
    const int tid = threadIdx.x, wg = blockIdx.x;
    for (int b = tid; b < NB; b += 1024)
        lcur[b] = cntmat[b * NWG_P + wg] + bbase[b];
    __syncthreads();
    const int r0 = wg * per_wg, r1 = min(E, r0 + per_wg);
    for (int e = r0 + tid; e < r1; e += 1024) {
        int s = ei[e], d = ei[E + e];
        int b = d >> 8;
        int pos = atomicAdd(&lcur[b], 1);
        tmp[pos] = ((unsigned)(d & 255) << 24) | (unsigned)s;
    }
}

// P2: one WG per bucket. Self-inclusive adjacency (ssrc = byte offsets),
// dinv, degree counting-sort -> order[], fused prescale xh = fp16(dinv*x).
__global__ __launch_bounds__(256) void k_p2(const unsigned* __restrict__ tmp,
                                            const int* __restrict__ bbase,
                                            const float* __restrict__ x,
                                            int* __restrict__ rstart,
                                            int* __restrict__ cnt,
                                            float* __restrict__ dinv,
                                            int* __restrict__ ssrc,
                                            int* __restrict__ order,
                                            _Float16* __restrict__ xh, int N) {
    __shared__ int nh[256];
    __shared__ int sd[256];
    __shared__ int curs[256];
    __shared__ float dvv[256];
    __shared__ int dh[64];
    __shared__ int dbase[64];
    const int tid = threadIdx.x;
    const int b = blockIdx.x;
    const int node0 = b << 8;
    const int e0 = bbase[b], e1 = bbase[b + 1];
    nh[tid] = 0;
    __syncthreads();
    for (int e = e0 + tid; e < e1; e += 256)
        atomicAdd(&nh[tmp[e] >> 24], 1);
    __syncthreads();
    const int v = nh[tid];
    sd[tid] = v;
    for (int off = 1; off < 256; off <<= 1) {
        __syncthreads();
        int t = (tid >= off) ? sd[tid - off] : 0;
        __syncthreads();
        sd[tid] += t;
    }
    __syncthreads();
    const int rs = e0 + node0 + (sd[tid] - v) + tid;   // self-inclusive layout
    const int node = node0 + tid;
    const bool valid = (node < N);
    if (valid) {
        rstart[node] = rs;
        cnt[node] = v + 1;
        const float dv = rsqrtf((float)v + 1.0f);
        dinv[node] = dv;
        dvv[tid] = dv;
        ssrc[rs] = node << 7;              // self entry (byte offset)
    }
    curs[tid] = rs + 1;
    if (tid < 64) dh[tid] = 0;
    __syncthreads();
    // degree counting-sort into order[] (bucket-local; bin = min(deg,63))
    const int bin = min(v, 63);
    int posInBin = 0;
    if (valid) posInBin = atomicAdd(&dh[bin], 1);
    __syncthreads();
    if (tid < 64) {                        // wave-0 exclusive scan of 64 bins
        const int xv = dh[tid];
        int s = xv;
        for (int off = 1; off < 64; off <<= 1) {
            int y = __shfl_up(s, off);
            if (tid >= off) s += y;
        }
        dbase[tid] = s - xv;
    }
    __syncthreads();
    if (valid) order[node0 + dbase[bin] + posInBin] = node;
    // fused prescale: xh = fp16(dinv * x) for this bucket's rows
    const int nrows = min(256, N - node0);
    for (int i = tid; i < nrows * 16; i += 256) {
        const int r = i >> 4, c4 = i & 15;
        const float dv = dvv[r];
        const float4 vv = *(const float4*)&x[(((size_t)(node0 + r)) << 6) + c4 * 4];
        half4v o;
        o[0] = (_Float16)(dv * vv.x); o[1] = (_Float16)(dv * vv.y);
        o[2] = (_Float16)(dv * vv.z); o[3] = (_Float16)(dv * vv.w);
        *(half4v*)(xh + (((size_t)(node0 + r)) << 6) + c4 * 4) = o;
    }
    // permute edges into final slots (byte offsets)
    for (int e = e0 + tid; e < e1; e += 256) {
        const unsigned p = tmp[e];
        const int slot = atomicAdd(&curs[p >> 24], 1);
        ssrc[slot] = (int)(p & 0xFFFFFFu) << 7;
    }
}

// ---------------- weight prep + zero rows ----------------
// B frag (16x16x32): lane holds B[k = quad*8+j][n = lane&15], j=0..7.

__global__ __launch_bounds__(256) void k_prep(const float* __restrict__ W1,
                                              const float* __restrict__ W2,
                                              _Float16* __restrict__ w1f,
                                              _Float16* __restrict__ w2f,
                                              _Float16* __restrict__ xh,
                                              _Float16* __restrict__ yh, int N) {
    const int idx = blockIdx.x * 256 + threadIdx.x;
    if (idx < 1024) {                       // W1: nt 0..7, kk 0..1, lane
        const int lane = idx & 63;
        const int kk = (idx >> 6) & 1;
        const int nt = idx >> 7;
        const int quad = lane >> 4, col = lane & 15;
        half8 o;
#pragma unroll
        for (int j = 0; j < 8; ++j) {
            const int k = kk * 32 + quad * 8 + j;
            const int n = nt * 16 + col;
            o[j] = (_Float16)W1[k * HID + n];
        }
        *(half8*)(w1f + (size_t)idx * 8) = o;
    } else if (idx < 1024 + 768) {          // W2: nt 0..2, kk 0..3, lane (n pad 48)
        const int i2 = idx - 1024;
        const int lane = i2 & 63;
        const int kk = (i2 >> 6) & 3;
        const int nt = i2 >> 8;
        const int quad = lane >> 4, col = lane & 15;
        half8 o;
#pragma unroll
        for (int j = 0; j < 8; ++j) {
            const int k = kk * 32 + quad * 8 + j;
            const int n = nt * 16 + col;
            o[j] = (n < CLS) ? (_Float16)W2[k * CLS + n] : (_Float16)0.f;
        }
        *(half8*)(w2f + (size_t)i2 * 8) = o;
    } else if (idx < 1024 + 768 + 64) {     // zero rows xh[N], yh[N]
        const int t = idx - 1792;
        xh[(size_t)N * 64 + t] = (_Float16)0;
        yh[(size_t)N * 64 + t] = (_Float16)0;
    }
}

// ---------------- degree-ordered group-per-row packed fp16 gather -----------
// X: fp16 rows of 64 halves (128B), row N = zeros. Wave handles 8 rows taken
// from order[] (degree-adjacent -> near-uniform loop bounds). Group g (8
// lanes) owns row order[wave*8+g]; lane owns 16B chunk sub. Edges accumulate
// serially in-lane (4 pk_add each) — no cross-lane reduction. Per-group loop
// bound; tail slots load the zero row. ssrc entries are BYTE offsets.

template <bool HALF_OUT, int FOUT, bool BIAS>
__global__ __launch_bounds__(256) void k_gather8(const _Float16* __restrict__ X,
                                                 const float* __restrict__ dinv,
                                                 const int* __restrict__ rstart,
                                                 const int* __restrict__ cnt,
                                                 const int* __restrict__ ssrc,
                                                 const int* __restrict__ order,
                                                 const float* __restrict__ bias,
                                                 void* __restrict__ outv,
                                                 int N, int zoff) {
    const int wave = (blockIdx.x * 256 + threadIdx.x) >> 6;
    const int lane = threadIdx.x & 63;
    const int g = lane >> 3, sub = lane & 7;
    const int r = order[min(wave * 8 + g, N - 1)];   // tail groups duplicate
    const int st = rstart[r];
    const int total = cnt[r];              // self-inclusive, >= 1
    const char* Xb = (const char*)X;
    half2v acc2[4] = {half2v{0, 0}, half2v{0, 0}, half2v{0, 0}, half2v{0, 0}};
    for (int base = 0; base < total; base += 8) {
        const int idx = base + sub;
        int myO = ssrc[st + min(idx, total - 1)];
        myO = (idx < total) ? myO : zoff;  // OOB -> zero row
#pragma unroll
        for (int jj = 0; jj < 8; ++jj) {
            const int off = __shfl(myO, g * 8 + jj);
            const half8 hv = *(const half8*)(Xb + off + (sub << 4));
            const half2v* h2 = (const half2v*)&hv;
            acc2[0] += h2[0]; acc2[1] += h2[1];
            acc2[2] += h2[2]; acc2[3] += h2[3];
        }
    }
    const float dv = dinv[r];
    float acc[8];
#pragma unroll
    for (int k = 0; k < 8; ++k) acc[k] = (float)acc2[k >> 1][k & 1] * dv;
    if (HALF_OUT) {
        half8 o;
#pragma unroll
        for (int k = 0; k < 8; ++k) o[k] = (_Float16)acc[k];
        *(half8*)((_Float16*)outv + ((size_t)r << 6) + (sub << 3)) = o;
    } else {
        const int f0 = sub * 8;
        if (f0 < FOUT) {
            if (BIAS) {
                float4 bb0 = *(const float4*)&bias[f0];
                float4 bb1 = *(const float4*)&bias[f0 + 4];
                acc[0] += bb0.x; acc[1] += bb0.y; acc[2] += bb0.z; acc[3] += bb0.w;
                acc[4] += bb1.x; acc[5] += bb1.y; acc[6] += bb1.z; acc[7] += bb1.w;
            }
            float* op = (float*)outv + (size_t)r * FOUT + f0;
            *(float4*)op = make_float4(acc[0], acc[1], acc[2], acc[3]);
            *(float4*)(op + 4) = make_float4(acc[4], acc[5], acc[6], acc[7]);
        }
    }
}

// ---------------- fused MFMA MLP: t -> h (regs) -> yh ----------------

__global__ __launch_bounds__(256, 3) void k_mlp(const _Float16* __restrict__ th,
                                                const _Float16* __restrict__ w1f,
                                                const float* __restrict__ b1,
                                                const _Float16* __restrict__ w2f,
                                                const float* __restrict__ dinv,
                                                _Float16* __restrict__ yh, int N) {
    __shared__ _Float16 hbuf[4][16 * 128];  // 16 KB
    const int tid = threadIdx.x;
    const int wave = tid >> 6, lane = tid & 63;
    const int quad = lane >> 4, col = lane & 15;
    const int row0 = blockIdx.x * 64 + wave * 16;
    const int arow = min(row0 + col, N - 1);
    const half8 a0 = *(const half8*)(th + ((size_t)arow << 6) + quad * 8);
    const half8 a1 = *(const half8*)(th + ((size_t)arow << 6) + 32 + quad * 8);
    floatx4 c[8];
#pragma unroll
    for (int nt = 0; nt < 8; ++nt) {
        c[nt] = (floatx4){0.f, 0.f, 0.f, 0.f};
        const half8 bb0 = *(const half8*)(w1f + (size_t)((nt * 2 + 0) * 64 + lane) * 8);
        const half8 bb1 = *(const half8*)(w1f + (size_t)((nt * 2 + 1) * 64 + lane) * 8);
        c[nt] = __builtin_amdgcn_mfma_f32_16x16x32_f16(a0, bb0, c[nt], 0, 0, 0);
        c[nt] = __builtin_amdgcn_mfma_f32_16x16x32_f16(a1, bb1, c[nt], 0, 0, 0);
    }
    _Float16* hb = hbuf[wave];
#pragma unroll
    for (int nt = 0; nt < 8; ++nt) {
        const float bv = b1[nt * 16 + col];
#pragma unroll
        for (int reg = 0; reg < 4; ++reg) {
            const int r = quad * 4 + reg;
            const int hcol = nt * 16 + col;
            const int chunk = ((hcol >> 3) ^ r) & 15;
            hb[r * 128 + chunk * 8 + (hcol & 7)] =
                (_Float16)fmaxf(c[nt][reg] + bv, 0.f);
        }
    }
    __syncthreads();
    half8 a2[4];
#pragma unroll
    for (int kk = 0; kk < 4; ++kk) {
        const int chunk = ((kk * 4 + quad) ^ col) & 15;
        a2[kk] = *(const half8*)(hb + col * 128 + chunk * 8);
    }
    floatx4 c2[3];
#pragma unroll
    for (int nt = 0; nt < 3; ++nt) {
        c2[nt] = (floatx4){0.f, 0.f, 0.f, 0.f};
#pragma unroll
        for (int kk = 0; kk < 4; ++kk) {
            const half8 bb = *(const half8*)(w2f + (size_t)((nt * 4 + kk) * 64 + lane) * 8);
            c2[nt] = __builtin_amdgcn_mfma_f32_16x16x32_f16(a2[kk], bb, c2[nt], 0, 0, 0);
        }
    }
#pragma unroll
    for (int reg = 0; reg < 4; ++reg) {
        const int gr = row0 + quad * 4 + reg;
        const float dvr = dinv[min(gr, N - 1)];
#pragma unroll
        for (int nt = 0; nt < 3; ++nt) {
            const int cc = nt * 16 + col;
            if (gr < N && cc < CLS)
                yh[((size_t)gr << 6) + cc] = (_Float16)(c2[nt][reg] * dvr);
        }
    }
    for (int i = lane; i < 16 * 12; i += 64) {
        const int row = row0 + i / 12;
        if (row < N)
            ((unsigned*)(yh + ((size_t)row << 6)))[20 + i % 12] = 0u;
    }
}

// ---------------- launch ----------------

extern "C" void kernel_launch(void* const* d_in, const int* in_sizes, int n_in,
                              void* d_out, int out_size, void* d_ws, size_t ws_size,
                              hipStream_t stream) {
    const float* x  = (const float*)d_in[0];
    const int*   ei = (const int*)d_in[1];   // [2][E]
    const float* W1 = (const float*)d_in[2];
    const float* b1 = (const float*)d_in[3];
    const float* W2 = (const float*)d_in[4];
    const float* b2 = (const float*)d_in[5];
    float* out = (float*)d_out;

    const int N = in_sizes[0] / FIN;
    const int E = in_sizes[1] / 2;
    const int NB = (N + 255) >> 8;
    const int per_wg = (E + NWG_P - 1) / NWG_P;
    const int zoff = N << 7;                 // zero-row byte offset

    float* dinv    = (float*)d_ws;                       // N
    _Float16* th   = (_Float16*)(dinv + N);              // (N+1)*64
    _Float16* yh   = th + (size_t)(N + 1) * 64;          // (N+1)*64
    _Float16* xh   = yh + (size_t)(N + 1) * 64;          // (N+1)*64
    int* cnt       = (int*)(xh + (size_t)(N + 1) * 64);  // N
    int* rstart    = cnt + N;                            // N
    int* order     = rstart + N;                         // N
    int* ssrc      = order + N;                          // E + N
    int* cntmat    = ssrc + E + N;                       // NB_MAX*NWG_P
    int* btot      = cntmat + NB_MAX * NWG_P;            // NB_MAX
    int* bbase     = btot + NB_MAX;                      // NB_MAX+1
    unsigned* tmp  = (unsigned*)(bbase + NB_MAX + 1);    // E
    _Float16* w1f  = (_Float16*)(tmp + E);               // 8192
    _Float16* w2f  = w1f + 8192;                         // 6144

    dim3 blk(256);
    // CSR build (radix partition by dst)
    hipLaunchKernelGGL(k_cnt,    dim3(NWG_P), dim3(1024), 0, stream, ei + E, cntmat, E, NB, per_wg);
    hipLaunchKernelGGL(k_bscan1, dim3(NB), blk, 0, stream, cntmat, btot);
    hipLaunchKernelGGL(k_bscan2, dim3(1), dim3(512), 0, stream, btot, bbase, NB, E);
    hipLaunchKernelGGL(k_scat,   dim3(NWG_P), dim3(1024), 0, stream, ei, cntmat, bbase, tmp, E, NB, per_wg);
    // p2: node CSR + dinv + degree order + fused prescale
    hipLaunchKernelGGL(k_p2, dim3(NB), blk, 0, stream,
                       tmp, bbase, x, rstart, cnt, dinv, ssrc, order, xh, N);
    // weight prep + zero rows
    hipLaunchKernelGGL(k_prep, dim3(8), blk, 0, stream, W1, W2, w1f, w2f, xh, yh, N);
    // layer 1 aggregate -> fp16 t
    hipLaunchKernelGGL((k_gather8<true, FIN, false>), dim3((N + 31) / 32), blk, 0, stream,
                       xh, dinv, rstart, cnt, ssrc, order, (const float*)nullptr, (void*)th, N, zoff);
    // fused MFMA MLP: t -> h -> yh
    hipLaunchKernelGGL(k_mlp, dim3((N + 63) / 64), blk, 0, stream, th, w1f, b1, w2f, dinv, yh, N);
    // layer 2 aggregate + bias -> out
    hipLaunchKernelGGL((k_gather8<false, CLS, true>), dim3((N + 31) / 32), blk, 0, stream,
                       yh, dinv, rstart, cnt, ssrc, order, b2, (void*)out, N, zoff);
}